// Round 1
// baseline (212.802 us; speedup 1.0000x reference)
//
#include <hip/hip_runtime.h>

typedef __attribute__((ext_vector_type(8))) short bf16x8;
typedef __attribute__((ext_vector_type(4))) float f32x4;

#define T_STEPS 49
#define BM 16
#define OUTSTRIDE (4096*64)

__device__ __forceinline__ short f2bf(float x) {
  unsigned u = __builtin_bit_cast(unsigned, x);
  u += 0x7FFFu + ((u >> 16) & 1u);   // round-to-nearest-even
  return (short)(u >> 16);
}
__device__ __forceinline__ float bf2f(short b) {
  return __builtin_bit_cast(float, ((unsigned)(unsigned short)b) << 16);
}
__device__ __forceinline__ float fast_tanh(float x) {
  // tanh(x) = 1 - 2/(e^{2x}+1); e^{2x} = 2^{x*2*log2(e)}
  float e = __builtin_amdgcn_exp2f(x * 2.885390081777927f);
  return 1.f - 2.f * __builtin_amdgcn_rcpf(e + 1.f);
}

// One WG = 16 batch rows, 512 threads = 8 waves. Wave w owns H cols [32w,32w+32)
// in layer 1 and K cols [16w,16w+16) in layer 2. Weights (bf16 B-fragments) are
// register-resident for the whole 49-step integration; LDS only stages Y (hi/lo
// split) and H between the two layers.
__global__ __launch_bounds__(512)
void node_rk4_kernel(const float* __restrict__ x0, const float* __restrict__ tarr,
                     const float* __restrict__ W1, const float* __restrict__ b1,
                     const float* __restrict__ W2, const float* __restrict__ b2,
                     float* __restrict__ out)
{
  __shared__ __align__(16) short Yhi[16][136];   // stride padded: 2-way banks only
  __shared__ __align__(16) short Ylo[16][136];
  __shared__ __align__(16) short Hbf[16][264];

  const int tid  = threadIdx.x;
  const int w    = tid >> 6;        // wave 0..7
  const int lane = tid & 63;
  const int m    = lane & 15;       // A-row / B-col / D-col index
  const int g    = lane >> 4;       // 0..3
  const int row0 = (int)blockIdx.x * BM;
  const int col  = 16*w + m;        // this lane's layer-2 output column

  // ---- load weight fragments into registers (one-time, L2-served) ----
  // intra-chunk K mapping: k = kk*32 + 8*g + j  (same for A and B -> safe)
  bf16x8 wB1[2][4], wB2[8];
#pragma unroll
  for (int tt = 0; tt < 2; ++tt)
#pragma unroll
    for (int kk = 0; kk < 4; ++kk) {
      bf16x8 v;
#pragma unroll
      for (int j = 0; j < 8; ++j)
        v[j] = f2bf(W1[(kk*32 + 8*g + j)*256 + (32*w + 16*tt + m)]);
      wB1[tt][kk] = v;
    }
#pragma unroll
  for (int kk = 0; kk < 8; ++kk) {
    bf16x8 v;
#pragma unroll
    for (int j = 0; j < 8; ++j)
      v[j] = f2bf(W2[(kk*32 + 8*g + j)*128 + col]);
    wB2[kk] = v;
  }
  const float bb1a = b1[32*w + m];
  const float bb1b = b1[32*w + 16 + m];
  const float bb2  = b2[col];

  // ---- per-lane fp32 state: rows 4g+i, column `col` (C/D fragment layout) ----
  float y[4], k1[4], k2[4], k3[4], yn[4];
#pragma unroll
  for (int i = 0; i < 4; ++i) {
    float v = (col < 64) ? x0[(row0 + 4*g + i)*64 + col] : 0.f;
    y[i] = v; yn[i] = v;
  }
  if (col < 64) {   // sol[0] = x0
#pragma unroll
    for (int i = 0; i < 4; ++i)
      out[(row0 + 4*g + i)*64 + col] = y[i];
  }

  for (int step = 0; step < T_STEPS; ++step) {
    const float dt = tarr[step+1] - tarr[step];
    const float third = dt * (1.f/3.f);

#pragma unroll
    for (int stage = 0; stage < 4; ++stage) {
      // stage input -> LDS, hi/lo bf16 split (kills y-quantization error)
#pragma unroll
      for (int i = 0; i < 4; ++i) {
        short hi = f2bf(yn[i]);
        float r  = yn[i] - bf2f(hi);
        Yhi[4*g + i][col] = hi;
        Ylo[4*g + i][col] = f2bf(r);
      }
      __syncthreads();

      // layer 1: H = tanh(Y @ W1 + b1)
      f32x4 acc0 = { bb1a, bb1a, bb1a, bb1a };
      f32x4 acc1 = { bb1b, bb1b, bb1b, bb1b };
#pragma unroll
      for (int kk = 0; kk < 4; ++kk) {
        bf16x8 ah = *(const bf16x8*)&Yhi[m][kk*32 + 8*g];
        bf16x8 al = *(const bf16x8*)&Ylo[m][kk*32 + 8*g];
        acc0 = __builtin_amdgcn_mfma_f32_16x16x32_bf16(ah, wB1[0][kk], acc0, 0,0,0);
        acc1 = __builtin_amdgcn_mfma_f32_16x16x32_bf16(ah, wB1[1][kk], acc1, 0,0,0);
        acc0 = __builtin_amdgcn_mfma_f32_16x16x32_bf16(al, wB1[0][kk], acc0, 0,0,0);
        acc1 = __builtin_amdgcn_mfma_f32_16x16x32_bf16(al, wB1[1][kk], acc1, 0,0,0);
      }
#pragma unroll
      for (int i = 0; i < 4; ++i) {
        Hbf[4*g + i][32*w + m]      = f2bf(fast_tanh(acc0[i]));
        Hbf[4*g + i][32*w + 16 + m] = f2bf(fast_tanh(acc1[i]));
      }
      __syncthreads();

      // layer 2: K = H @ W2 + b2 (two independent acc chains for MFMA overlap)
      f32x4 accA = { bb2, bb2, bb2, bb2 };
      f32x4 accB = { 0.f, 0.f, 0.f, 0.f };
#pragma unroll
      for (int kk = 0; kk < 4; ++kk) {
        bf16x8 aA = *(const bf16x8*)&Hbf[m][kk*32 + 8*g];
        bf16x8 aB = *(const bf16x8*)&Hbf[m][(kk+4)*32 + 8*g];
        accA = __builtin_amdgcn_mfma_f32_16x16x32_bf16(aA, wB2[kk],   accA, 0,0,0);
        accB = __builtin_amdgcn_mfma_f32_16x16x32_bf16(aB, wB2[kk+4], accB, 0,0,0);
      }

      // RK4 (3/8 rule) bookkeeping, fully per-lane in fp32
      if (stage == 0) {
#pragma unroll
        for (int i = 0; i < 4; ++i) { k1[i] = accA[i]+accB[i]; yn[i] = y[i] + third*k1[i]; }
      } else if (stage == 1) {
#pragma unroll
        for (int i = 0; i < 4; ++i) { k2[i] = accA[i]+accB[i]; yn[i] = y[i] + dt*(k2[i] - k1[i]*(1.f/3.f)); }
      } else if (stage == 2) {
#pragma unroll
        for (int i = 0; i < 4; ++i) { k3[i] = accA[i]+accB[i]; yn[i] = y[i] + dt*(k1[i] - k2[i] + k3[i]); }
      } else {
#pragma unroll
        for (int i = 0; i < 4; ++i) {
          float k4 = accA[i]+accB[i];
          y[i] += dt*0.125f*(k1[i] + 3.f*(k2[i]+k3[i]) + k4);
          yn[i] = y[i];
        }
        if (col < 64) {
#pragma unroll
          for (int i = 0; i < 4; ++i)
            out[(step+1)*OUTSTRIDE + (row0 + 4*g + i)*64 + col] = y[i];
        }
      }
    }
  }
}

extern "C" void kernel_launch(void* const* d_in, const int* in_sizes, int n_in,
                              void* d_out, int out_size, void* d_ws, size_t ws_size,
                              hipStream_t stream) {
  const float* x0 = (const float*)d_in[0];
  const float* t  = (const float*)d_in[1];
  const float* W1 = (const float*)d_in[2];
  const float* b1 = (const float*)d_in[3];
  const float* W2 = (const float*)d_in[4];
  const float* b2 = (const float*)d_in[5];
  float* out = (float*)d_out;
  hipLaunchKernelGGL(node_rk4_kernel, dim3(4096/BM), dim3(512), 0, stream,
                     x0, t, W1, b1, W2, b2, out);
}